// Round 1
// 228.594 us; speedup vs baseline: 1.0202x; 1.0202x over previous
//
#include <hip/hip_runtime.h>

// PennSkipGramModel forward: mean over B of
//   -logsig(clip(u_l·v_l)) + -logsig(clip(u_r·v_r))
//   + sum_k -logsig(-clip(u_l·neg_l[k])) + sum_k -logsig(-clip(u_r·neg_r[k]))
//
// Layout: 16 lanes per batch element; lane j holds row float4s #j and #(j+16)
// (row = 128 fp32 = 32 float4).
//
// This version: FULL PREFETCH. All 13 indices load first (independent), then
// all 28 row float4-loads issue back-to-back into named registers, then all
// compute. Issue order == use order, so the compiler's waitcnt insertion
// drains partially: pos scores compute while the 20 neg-row loads are still
// in flight. __launch_bounds__(256,3) relaxes the VGPR cap to ~168 so the
// whole payload (112 VGPRs) can stay live; a sched_barrier pins the loads
// above the compute so the scheduler can't re-serialize them.

#define HV4   32        // float4s per 128-float row
#define BATCH 65536
#define K     5

__device__ __forceinline__ float dot4(float4 a, float4 b) {
    return a.x * b.x + a.y * b.y + a.z * b.z + a.w * b.w;
}

__device__ __forceinline__ float red16(float v) {
    v += __shfl_xor(v, 8, 16);
    v += __shfl_xor(v, 4, 16);
    v += __shfl_xor(v, 2, 16);
    v += __shfl_xor(v, 1, 16);
    return v;   // full sum in all 16 lanes
}

__device__ __forceinline__ float clip10(float x) {
    return fminf(fmaxf(x, -10.0f), 10.0f);
}

__global__ __launch_bounds__(256, 3) void skipgram_fwd(
    const float* __restrict__ u_l, const float* __restrict__ u_r,
    const float* __restrict__ v_l, const float* __restrict__ v_r,
    const int* __restrict__ pos_u, const int* __restrict__ pos_vl,
    const int* __restrict__ pos_vr, const int* __restrict__ neg_vl,
    const int* __restrict__ neg_vr, float* __restrict__ out)
{
    const int tid  = threadIdx.x;
    const int lane = tid & 15;      // lane within 16-lane group
    const int grp  = tid >> 4;      // 0..15 groups per block
    const int b    = (blockIdx.x << 4) + grp;

    // ---- phase 0: all index loads (13 independent scalars) ----
    const int iu  = pos_u[b];
    const int ivl = pos_vl[b];
    const int ivr = pos_vr[b];
    int inl[K], inr[K];
    #pragma unroll
    for (int k = 0; k < K; ++k) {
        inl[k] = neg_vl[b * K + k];
        inr[k] = neg_vr[b * K + k];
    }

    // ---- phase 1: issue ALL 28 row loads, issue order == use order ----
    const float4* ULr = (const float4*)u_l + (size_t)iu * HV4;
    const float4* URr = (const float4*)u_r + (size_t)iu * HV4;
    float4 ul0 = ULr[lane], ul1 = ULr[lane + 16];
    float4 ur0 = URr[lane], ur1 = URr[lane + 16];

    const float4* VLr = (const float4*)v_l + (size_t)ivl * HV4;
    const float4* VRr = (const float4*)v_r + (size_t)ivr * HV4;
    float4 vl0 = VLr[lane], vl1 = VLr[lane + 16];
    float4 vr0 = VRr[lane], vr1 = VRr[lane + 16];

    float4 nl0[K], nl1[K], nr0[K], nr1[K];
    #pragma unroll
    for (int k = 0; k < K; ++k) {
        const float4* NL = (const float4*)v_l + (size_t)inl[k] * HV4;
        const float4* NR = (const float4*)v_r + (size_t)inr[k] * HV4;
        nl0[k] = NL[lane]; nl1[k] = NL[lane + 16];
        nr0[k] = NR[lane]; nr1[k] = NR[lane + 16];
    }

    // Pin all loads above the compute: the scheduler may not sink them back
    // into the reduction chain (that is exactly the 36-VGPR serialization
    // this version removes).
    __builtin_amdgcn_sched_barrier(0);

    // ---- phase 2: compute; waitcnt drains partially in issue order ----
    float sl = red16(dot4(ul0, vl0) + dot4(ul1, vl1));
    float sr = red16(dot4(ur0, vr0) + dot4(ur1, vr1));

    // -log_sigmoid(x) = log(1 + exp(-x)),  x already clipped to [-10,10]
    float acc = __logf(1.0f + __expf(-clip10(sl)))
              + __logf(1.0f + __expf(-clip10(sr)));

    #pragma unroll
    for (int k = 0; k < K; ++k) {
        float snl = red16(dot4(ul0, nl0[k]) + dot4(ul1, nl1[k]));
        float snr = red16(dot4(ur0, nr0[k]) + dot4(ur1, nr1[k]));
        // -log_sigmoid(-x) = log(1 + exp(x))
        acc += __logf(1.0f + __expf(clip10(snl)))
             + __logf(1.0f + __expf(clip10(snr)));
    }

    // block reduction: one value per 16-lane group -> one atomic per block
    __shared__ float smem[16];
    if (lane == 0) smem[grp] = acc;
    __syncthreads();
    if (tid == 0) {
        float s = 0.0f;
        #pragma unroll
        for (int i = 0; i < 16; ++i) s += smem[i];
        atomicAdd(out, s * (1.0f / BATCH));
    }
}

extern "C" void kernel_launch(void* const* d_in, const int* in_sizes, int n_in,
                              void* d_out, int out_size, void* d_ws, size_t ws_size,
                              hipStream_t stream) {
    const float* u_l   = (const float*)d_in[0];
    const float* u_r   = (const float*)d_in[1];
    const float* v_l   = (const float*)d_in[2];
    const float* v_r   = (const float*)d_in[3];
    const int* pos_u   = (const int*)d_in[4];
    const int* pos_vl  = (const int*)d_in[5];
    const int* pos_vr  = (const int*)d_in[6];
    const int* neg_vl  = (const int*)d_in[7];
    const int* neg_vr  = (const int*)d_in[8];
    float* out = (float*)d_out;

    // d_out is poisoned (0xAA) before every timed launch — zero it on-stream.
    hipMemsetAsync(out, 0, sizeof(float), stream);

    skipgram_fwd<<<BATCH / 16, 256, 0, stream>>>(
        u_l, u_r, v_l, v_r, pos_u, pos_vl, pos_vr, neg_vl, neg_vr, out);
}